// Round 1
// baseline (137.286 us; speedup 1.0000x reference)
//
#include <hip/hip_runtime.h>
#include <math.h>

#define N_NODES  32
#define N_HEADS  4
#define HEAD_DIM 64
#define CDIM     256           // N_HEADS * HEAD_DIM == channels
#define HWPIX    9216          // 96*96
#define E_BASE   512
#define E_TOT    544           // + 32 self loops
#define NEG_SLOPE 0.2f

// ---------------------------------------------------------------------------
// Kernel 1: spatial mean pool.  roi [32,256,96,96] -> x [32,256]
// One block per (n,c) row: 9216 floats = 2304 float4; 256 threads x 9 float4.
// ---------------------------------------------------------------------------
__global__ __launch_bounds__(256) void pool_kernel(const float* __restrict__ roi,
                                                   float* __restrict__ x) {
    const int row = blockIdx.x;                       // 0..8191  (n*256+c)
    const float4* p = reinterpret_cast<const float4*>(roi) + (size_t)row * (HWPIX / 4);
    float s = 0.f;
#pragma unroll
    for (int i = 0; i < 9; ++i) {
        float4 v = p[threadIdx.x + i * 256];
        s += (v.x + v.y) + (v.z + v.w);
    }
#pragma unroll
    for (int off = 32; off; off >>= 1) s += __shfl_down(s, off);
    __shared__ float red[4];
    const int lane = threadIdx.x & 63, wv = threadIdx.x >> 6;
    if (lane == 0) red[wv] = s;
    __syncthreads();
    if (threadIdx.x == 0)
        x[row] = (red[0] + red[1] + red[2] + red[3]) * (1.0f / (float)HWPIX);
}

// ---------------------------------------------------------------------------
// Kernel 2: h = x @ W  (per-node), plus alpha_s/alpha_d head reductions.
// grid = 32 (one block per node), block = 256 (one thread per output column).
// ---------------------------------------------------------------------------
__global__ __launch_bounds__(256) void h_kernel(const float* __restrict__ x,
                                                const float* __restrict__ W,
                                                const float* __restrict__ a_src,
                                                const float* __restrict__ a_dst,
                                                float* __restrict__ h,
                                                float* __restrict__ alpha_s,
                                                float* __restrict__ alpha_d) {
    const int n = blockIdx.x, t = threadIdx.x;
    __shared__ float xs[CDIM];
    xs[t] = x[n * CDIM + t];
    __syncthreads();
    float acc = 0.f;
#pragma unroll 8
    for (int c = 0; c < CDIM; ++c) acc += xs[c] * W[c * CDIM + t];
    h[n * CDIM + t] = acc;

    const int head = t >> 6, f = t & 63;              // wave w == head w
    float ps = acc * a_src[head * HEAD_DIM + f];
    float pd = acc * a_dst[head * HEAD_DIM + f];
#pragma unroll
    for (int off = 32; off; off >>= 1) {
        ps += __shfl_down(ps, off);
        pd += __shfl_down(pd, off);
    }
    if (f == 0) {
        alpha_s[n * N_HEADS + head] = ps;
        alpha_d[n * N_HEADS + head] = pd;
    }
}

// ---------------------------------------------------------------------------
// Kernel 3 (single block, 256 threads): edges -> LeakyReLU -> segment softmax
// -> dense per-head attention matrix -> aggregation -> SiLU -> classifier.
// LDS: 4352 + 8704 + 2048 + 16384 + 32768 = 64256 B  (<= 64 KiB)
// ---------------------------------------------------------------------------
__global__ __launch_bounds__(256) void gat_kernel(const int* __restrict__ edge_index,
                                                  const float* __restrict__ h,
                                                  const float* __restrict__ alpha_s,
                                                  const float* __restrict__ alpha_d,
                                                  const float* __restrict__ gat_bias,
                                                  const float* __restrict__ cls_W,
                                                  const float* __restrict__ cls_b,
                                                  float* __restrict__ out) {
    __shared__ int   esrc[E_TOT], edst[E_TOT];
    __shared__ float esc[E_TOT * N_HEADS];            // per-edge per-head score
    __shared__ float as_[N_NODES * N_HEADS], ad_[N_NODES * N_HEADS];
    __shared__ float mseg[N_NODES * N_HEADS], dseg[N_NODES * N_HEADS];
    __shared__ float Mden[N_NODES][N_NODES * N_HEADS]; // [dst][src*4+head]
    __shared__ float sv[N_NODES][CDIM];               // silu(gat_out)

    const int t = threadIdx.x;

    // load edges (+ self loops appended, matching reference concat order)
    for (int e = t; e < E_BASE; e += 256) {
        esrc[e] = edge_index[e];
        edst[e] = edge_index[E_BASE + e];
    }
    if (t < (E_TOT - E_BASE)) {                       // 32 self loops
        esrc[E_BASE + t] = t;
        edst[E_BASE + t] = t;
    }
    if (t < N_NODES * N_HEADS) {
        as_[t] = alpha_s[t];
        ad_[t] = alpha_d[t];
        dseg[t] = 0.f;
    }
    for (int i = t; i < N_NODES * N_NODES * N_HEADS; i += 256)
        (&Mden[0][0])[i] = 0.f;
    __syncthreads();

    // per-edge LeakyReLU scores
    for (int i = t; i < E_TOT * N_HEADS; i += 256) {
        const int e = i >> 2, hd = i & 3;
        float v = as_[esrc[e] * N_HEADS + hd] + ad_[edst[e] * N_HEADS + hd];
        esc[i] = (v >= 0.f) ? v : NEG_SLOPE * v;
    }
    __syncthreads();

    // segment max per (dst, head)
    if (t < N_NODES * N_HEADS) {
        const int d = t >> 2, hd = t & 3;
        float mx = -INFINITY;
        for (int e = 0; e < E_TOT; ++e)
            if (edst[e] == d) mx = fmaxf(mx, esc[e * N_HEADS + hd]);
        mseg[t] = mx;
    }
    __syncthreads();

    // exp and segment sum (denominator)
    for (int i = t; i < E_TOT * N_HEADS; i += 256) {
        const int e = i >> 2, hd = i & 3;
        float a = expf(esc[i] - mseg[edst[e] * N_HEADS + hd]);
        esc[i] = a;
        atomicAdd(&dseg[edst[e] * N_HEADS + hd], a);
    }
    __syncthreads();

    // dense attention matrix (duplicate edges sum their alphas -> correct)
    for (int i = t; i < E_TOT * N_HEADS; i += 256) {
        const int e = i >> 2, hd = i & 3;
        const int d = edst[e], s0 = esrc[e];
        atomicAdd(&Mden[d][s0 * N_HEADS + hd], esc[i] / dseg[d * N_HEADS + hd]);
    }
    __syncthreads();

    // aggregation: thread t owns output column t; acc over src nodes
    const int head = t >> 6;
    float acc[N_NODES];
#pragma unroll
    for (int n = 0; n < N_NODES; ++n) acc[n] = 0.f;
    for (int s = 0; s < N_NODES; ++s) {
        const float hv = h[s * CDIM + t];
#pragma unroll
        for (int n = 0; n < N_NODES; ++n)
            acc[n] += Mden[n][s * N_HEADS + head] * hv;
    }
    const float b = gat_bias[t];
#pragma unroll
    for (int n = 0; n < N_NODES; ++n) {
        const float v = acc[n] + b;
        sv[n][t] = v / (1.0f + expf(-v));             // SiLU
    }
    __syncthreads();

    // classifier: logit[n][j] = silu_row(n) . cls_W[:,j] + cls_b[j]
    for (int o = t; o < N_NODES * 32; o += 256) {
        const int n = o >> 5, j = o & 31;
        float a = cls_b[j];
#pragma unroll 8
        for (int c = 0; c < CDIM; ++c) a += sv[n][c] * cls_W[c * 32 + j];
        out[n * 32 + j] = a;
    }
}

// ---------------------------------------------------------------------------
extern "C" void kernel_launch(void* const* d_in, const int* in_sizes, int n_in,
                              void* d_out, int out_size, void* d_ws, size_t ws_size,
                              hipStream_t stream) {
    const float* roi   = (const float*)d_in[0];
    const int*   eidx  = (const int*)d_in[1];
    const float* W     = (const float*)d_in[2];
    const float* a_src = (const float*)d_in[3];
    const float* a_dst = (const float*)d_in[4];
    const float* gbias = (const float*)d_in[5];
    const float* clsW  = (const float*)d_in[6];
    const float* clsb  = (const float*)d_in[7];
    float* out = (float*)d_out;

    float* x   = (float*)d_ws;                 // 32*256 floats
    float* h   = x + N_NODES * CDIM;           // 32*256 floats
    float* as_ = h + N_NODES * CDIM;           // 128 floats
    float* ad_ = as_ + N_NODES * N_HEADS;      // 128 floats

    pool_kernel<<<N_NODES * CDIM, 256, 0, stream>>>(roi, x);
    h_kernel<<<N_NODES, 256, 0, stream>>>(x, W, a_src, a_dst, h, as_, ad_);
    gat_kernel<<<1, 256, 0, stream>>>(eidx, h, as_, ad_, gbias, clsW, clsb, out);
}

// Round 2
// 90.631 us; speedup vs baseline: 1.5148x; 1.5148x over previous
//
#include <hip/hip_runtime.h>
#include <math.h>

#define N_NODES  32
#define N_HEADS  4
#define HEAD_DIM 64
#define CDIM     256           // N_HEADS * HEAD_DIM == channels
#define HWPIX    9216          // 96*96
#define ROWF4    2304          // HWPIX/4 float4 per (n,c) row
#define E_BASE   512
#define E_TOT    544           // + 32 self loops
#define NEG_SLOPE 0.2f

// ---------------------------------------------------------------------------
// Kernel 1: spatial mean pool.  roi [32,256,96,96] -> x [32,256]
// One WAVE per (n,c) row: 64 lanes x 36 float4, 12-deep load chunks.
// No LDS, no barriers. grid = 8192 rows / 4 waves = 2048 blocks.
// ---------------------------------------------------------------------------
__global__ __launch_bounds__(256) void pool_kernel(const float* __restrict__ roi,
                                                   float* __restrict__ x) {
    const int wave = threadIdx.x >> 6, lane = threadIdx.x & 63;
    const int row = blockIdx.x * 4 + wave;            // 0..8191  (n*256+c)
    const float4* p = reinterpret_cast<const float4*>(roi) + (size_t)row * ROWF4;

    float s = 0.f;
#pragma unroll
    for (int ch = 0; ch < 3; ++ch) {                  // 3 chunks x 12 float4
        float4 v[12];
#pragma unroll
        for (int j = 0; j < 12; ++j) v[j] = p[lane + (ch * 12 + j) * 64];
#pragma unroll
        for (int j = 0; j < 12; ++j) s += (v[j].x + v[j].y) + (v[j].z + v[j].w);
    }
#pragma unroll
    for (int off = 32; off; off >>= 1) s += __shfl_down(s, off);
    if (lane == 0) x[row] = s * (1.0f / (float)HWPIX);
}

// ---------------------------------------------------------------------------
// Kernel 2: h = x @ W  (per-node), plus alpha_s/alpha_d head reductions.
// grid = 32 (one block per node), block = 256 (one thread per output column).
// ---------------------------------------------------------------------------
__global__ __launch_bounds__(256) void h_kernel(const float* __restrict__ x,
                                                const float* __restrict__ W,
                                                const float* __restrict__ a_src,
                                                const float* __restrict__ a_dst,
                                                float* __restrict__ h,
                                                float* __restrict__ alpha_s,
                                                float* __restrict__ alpha_d) {
    const int n = blockIdx.x, t = threadIdx.x;
    __shared__ float xs[CDIM];
    xs[t] = x[n * CDIM + t];
    __syncthreads();
    float acc = 0.f;
#pragma unroll 8
    for (int c = 0; c < CDIM; ++c) acc += xs[c] * W[c * CDIM + t];
    h[n * CDIM + t] = acc;

    const int head = t >> 6, f = t & 63;              // wave w == head w
    float ps = acc * a_src[head * HEAD_DIM + f];
    float pd = acc * a_dst[head * HEAD_DIM + f];
#pragma unroll
    for (int off = 32; off; off >>= 1) {
        ps += __shfl_down(ps, off);
        pd += __shfl_down(pd, off);
    }
    if (f == 0) {
        alpha_s[n * N_HEADS + head] = ps;
        alpha_d[n * N_HEADS + head] = pd;
    }
}

// ---------------------------------------------------------------------------
// Kernel 3 (single block, 256 threads): edges -> LeakyReLU -> segment softmax
// (atomicMax via order-preserving uint key) -> dense per-head attention matrix
// [head][dst][src] -> float4-broadcast aggregation -> SiLU -> LDS classifier.
// Manual 64 KiB LDS arena; phase-2 (cls_W) reuses dead phase-1 space.
// ---------------------------------------------------------------------------
__global__ __launch_bounds__(256) void gat_kernel(const int* __restrict__ edge_index,
                                                  const float* __restrict__ h,
                                                  const float* __restrict__ alpha_s,
                                                  const float* __restrict__ alpha_d,
                                                  const float* __restrict__ gat_bias,
                                                  const float* __restrict__ cls_W,
                                                  const float* __restrict__ cls_b,
                                                  float* __restrict__ out) {
    __shared__ __align__(16) char smem[65536];
    int*      esrc  = (int*)(smem);                 // [544]            -> 2176
    int*      edst  = (int*)(smem + 2176);          // [544]            -> 4352
    float*    as_   = (float*)(smem + 4352);        // [128]            -> 4864
    float*    ad_   = (float*)(smem + 4864);        // [128]            -> 5376
    unsigned* msegu = (unsigned*)(smem + 5376);     // [128]            -> 5888
    float*    dseg  = (float*)(smem + 5888);        // [128]            -> 6400
    float*    esc   = (float*)(smem + 6400);        // [544*4]          -> 15104
    float*    Magg  = (float*)(smem + 15104);       // [4][32][32]      -> 31488
    float*    sv    = (float*)(smem + 32768);       // [32][256]        -> 65536
    float*    clsw  = (float*)(smem);               // [256*32] phase 2 (0..32768)

    const int t = threadIdx.x;

    // load edges (+ self loops appended, matching reference concat order)
    for (int e = t; e < E_BASE; e += 256) {
        esrc[e] = edge_index[e];
        edst[e] = edge_index[E_BASE + e];
    }
    if (t < (E_TOT - E_BASE)) {                     // 32 self loops
        esrc[E_BASE + t] = t;
        edst[E_BASE + t] = t;
    }
    if (t < N_NODES * N_HEADS) {
        as_[t]   = alpha_s[t];
        ad_[t]   = alpha_d[t];
        msegu[t] = 0u;                              // decodes to < any finite float
        dseg[t]  = 0.f;
    }
    for (int i = t; i < N_HEADS * N_NODES * N_NODES; i += 256) Magg[i] = 0.f;
    __syncthreads();

    // per-edge LeakyReLU scores + segment max via monotone uint atomicMax
    for (int i = t; i < E_TOT * N_HEADS; i += 256) {
        const int e = i >> 2, hd = i & 3;
        float v = as_[esrc[e] * N_HEADS + hd] + ad_[edst[e] * N_HEADS + hd];
        v = (v >= 0.f) ? v : NEG_SLOPE * v;
        esc[i] = v;
        const int iv = __float_as_int(v);
        const unsigned key = (iv < 0) ? ~(unsigned)iv : ((unsigned)iv | 0x80000000u);
        atomicMax(&msegu[edst[e] * N_HEADS + hd], key);
    }
    __syncthreads();

    // exp(e - max) and segment sum (denominator)
    for (int i = t; i < E_TOT * N_HEADS; i += 256) {
        const int e = i >> 2, hd = i & 3;
        const unsigned key = msegu[edst[e] * N_HEADS + hd];
        const int im = (key & 0x80000000u) ? (int)(key & 0x7fffffffu) : (int)~key;
        const float a = expf(esc[i] - __int_as_float(im));
        esc[i] = a;
        atomicAdd(&dseg[edst[e] * N_HEADS + hd], a);
    }
    __syncthreads();

    // dense attention matrix [head][dst][src]; duplicate edges sum correctly
    for (int i = t; i < E_TOT * N_HEADS; i += 256) {
        const int e = i >> 2, hd = i & 3;
        const int d = edst[e], s0 = esrc[e];
        atomicAdd(&Magg[hd * (N_NODES * N_NODES) + d * N_NODES + s0],
                  esc[i] / dseg[d * N_HEADS + hd]);
    }
    __syncthreads();

    // aggregation: thread t owns output column t; h column pre-loaded to regs
    const int head = t >> 6;
    float hreg[N_NODES];
#pragma unroll
    for (int s = 0; s < N_NODES; ++s) hreg[s] = h[s * CDIM + t];
    const float bias = gat_bias[t];
#pragma unroll
    for (int n = 0; n < N_NODES; ++n) {
        float acc = 0.f;
        const float4* mrow =
            (const float4*)(Magg + head * (N_NODES * N_NODES) + n * N_NODES);
#pragma unroll
        for (int sq = 0; sq < 8; ++sq) {            // 4 src per b128 broadcast
            const float4 m4 = mrow[sq];
            acc += m4.x * hreg[sq * 4 + 0] + m4.y * hreg[sq * 4 + 1]
                 + m4.z * hreg[sq * 4 + 2] + m4.w * hreg[sq * 4 + 3];
        }
        const float v = acc + bias;
        sv[n * CDIM + t] = v / (1.0f + expf(-v));   // SiLU
    }
    __syncthreads();

    // stage cls_W (32 KiB) into LDS, overwriting dead phase-1 arena
    for (int i = t; i < (CDIM * 32) / 4; i += 256)
        ((float4*)clsw)[i] = ((const float4*)cls_W)[i];
    __syncthreads();

    // classifier: logit[n][j] = silu_row(n) . cls_W[:,j] + cls_b[j]
    const int j = t & 31, g = t >> 5;
#pragma unroll
    for (int k = 0; k < 4; ++k) {
        const int n = g + k * 8;
        float a = cls_b[j];
#pragma unroll 8
        for (int c = 0; c < CDIM; ++c) a += sv[n * CDIM + c] * clsw[c * 32 + j];
        out[n * 32 + j] = a;
    }
}

// ---------------------------------------------------------------------------
extern "C" void kernel_launch(void* const* d_in, const int* in_sizes, int n_in,
                              void* d_out, int out_size, void* d_ws, size_t ws_size,
                              hipStream_t stream) {
    const float* roi   = (const float*)d_in[0];
    const int*   eidx  = (const int*)d_in[1];
    const float* W     = (const float*)d_in[2];
    const float* a_src = (const float*)d_in[3];
    const float* a_dst = (const float*)d_in[4];
    const float* gbias = (const float*)d_in[5];
    const float* clsW  = (const float*)d_in[6];
    const float* clsb  = (const float*)d_in[7];
    float* out = (float*)d_out;

    float* x   = (float*)d_ws;                 // 32*256 floats
    float* h   = x + N_NODES * CDIM;           // 32*256 floats
    float* as_ = h + N_NODES * CDIM;           // 128 floats
    float* ad_ = as_ + N_NODES * N_HEADS;      // 128 floats

    pool_kernel<<<(N_NODES * CDIM) / 4, 256, 0, stream>>>(roi, x);
    h_kernel<<<N_NODES, 256, 0, stream>>>(x, W, a_src, a_dst, h, as_, ad_);
    gat_kernel<<<1, 256, 0, stream>>>(eidx, h, as_, ad_, gbias, clsW, clsb, out);
}

// Round 3
// 78.894 us; speedup vs baseline: 1.7401x; 1.1488x over previous
//
#include <hip/hip_runtime.h>
#include <math.h>

#define N_NODES  32
#define N_HEADS  4
#define HEAD_DIM 64
#define CDIM     256           // N_HEADS * HEAD_DIM == channels
#define HWPIX    9216          // 96*96
#define ROWF4    2304          // HWPIX/4 float4 per (n,c) row
#define E_BASE   512
#define E_TOT    544           // + 32 self loops
#define NEG_SLOPE 0.2f

// ---------------------------------------------------------------------------
// Kernel 1: spatial mean pool.  roi [32,256,96,96] -> x [32,256]
// One WAVE per (n,c) row: 64 lanes x 36 float4, 9-deep load chunks (36 data
// VGPRs -> fits 64-VGPR budget for 8 waves/SIMD). No LDS, no barriers.
// ---------------------------------------------------------------------------
__global__ __launch_bounds__(256, 8) void pool_kernel(const float* __restrict__ roi,
                                                      float* __restrict__ x) {
    const int wave = threadIdx.x >> 6, lane = threadIdx.x & 63;
    const int row = blockIdx.x * 4 + wave;            // 0..8191  (n*256+c)
    const float4* p = reinterpret_cast<const float4*>(roi) + (size_t)row * ROWF4;

    float s = 0.f;
#pragma unroll
    for (int ch = 0; ch < 4; ++ch) {                  // 4 chunks x 9 float4
        float4 v[9];
#pragma unroll
        for (int j = 0; j < 9; ++j) v[j] = p[lane + (ch * 9 + j) * 64];
#pragma unroll
        for (int j = 0; j < 9; ++j) s += (v[j].x + v[j].y) + (v[j].z + v[j].w);
    }
#pragma unroll
    for (int off = 32; off; off >>= 1) s += __shfl_down(s, off);
    if (lane == 0) x[row] = s * (1.0f / (float)HWPIX);
}

// ---------------------------------------------------------------------------
// Kernel 2: h = x @ W  (per-node), plus alpha_s/alpha_d head reductions.
// grid = 32 (one block per node), block = 256 (one thread per output column).
// ---------------------------------------------------------------------------
__global__ __launch_bounds__(256) void h_kernel(const float* __restrict__ x,
                                                const float* __restrict__ W,
                                                const float* __restrict__ a_src,
                                                const float* __restrict__ a_dst,
                                                float* __restrict__ h,
                                                float* __restrict__ alpha_s,
                                                float* __restrict__ alpha_d) {
    const int n = blockIdx.x, t = threadIdx.x;
    __shared__ float xs[CDIM];
    xs[t] = x[n * CDIM + t];
    __syncthreads();
    float acc = 0.f;
#pragma unroll 8
    for (int c = 0; c < CDIM; ++c) acc += xs[c] * W[c * CDIM + t];
    h[n * CDIM + t] = acc;

    const int head = t >> 6, f = t & 63;              // wave w == head w
    float ps = acc * a_src[head * HEAD_DIM + f];
    float pd = acc * a_dst[head * HEAD_DIM + f];
#pragma unroll
    for (int off = 32; off; off >>= 1) {
        ps += __shfl_down(ps, off);
        pd += __shfl_down(pd, off);
    }
    if (f == 0) {
        alpha_s[n * N_HEADS + head] = ps;
        alpha_d[n * N_HEADS + head] = pd;
    }
}

// ---------------------------------------------------------------------------
// Kernel 3: 32 blocks, one per DST node. Each block scans the (L2-hot) edge
// list, keeps only edges into its node, does the per-node softmax with tiny
// LDS atomics, builds its 32x4 attention row, aggregates, SiLU, classifies.
// cls_W staging is issued at kernel top so its latency hides under edges.
// ---------------------------------------------------------------------------
__global__ __launch_bounds__(256) void gat_kernel(const int* __restrict__ edge_index,
                                                  const float* __restrict__ h,
                                                  const float* __restrict__ alpha_s,
                                                  const float* __restrict__ alpha_d,
                                                  const float* __restrict__ gat_bias,
                                                  const float* __restrict__ cls_W,
                                                  const float* __restrict__ cls_b,
                                                  float* __restrict__ out) {
    const int n = blockIdx.x;                         // dst node this block owns
    const int t = threadIdx.x;

    __shared__ float    clsw[CDIM * 32];              // 32 KiB
    __shared__ float    as_[N_NODES * N_HEADS];
    __shared__ float    adn[N_HEADS];
    __shared__ unsigned msegu[N_HEADS];
    __shared__ float    dseg[N_HEADS];
    __shared__ float    M[N_NODES][N_HEADS];          // attention row (by src)
    __shared__ float    sv[CDIM];
    __shared__ float    red[8][32];

    // stage cls_W into LDS; loads stay in flight during the edge phases
    for (int i = t; i < (CDIM * 32) / 4; i += 256)
        ((float4*)clsw)[i] = ((const float4*)cls_W)[i];

    if (t < N_NODES * N_HEADS) {
        as_[t] = alpha_s[t];
        ((float*)M)[t] = 0.f;
    }
    if (t < N_HEADS) {
        adn[t]   = alpha_d[n * N_HEADS + t];
        msegu[t] = 0u;                                // decodes below any finite
        dseg[t]  = 0.f;
    }
    __syncthreads();

    // pass A: segment max over edges into n (monotone uint atomicMax)
    for (int e = t; e < E_TOT; e += 256) {
        int s0, d;
        if (e < E_BASE) { s0 = edge_index[e]; d = edge_index[E_BASE + e]; }
        else            { s0 = e - E_BASE;    d = s0; }          // self loops
        if (d == n) {
#pragma unroll
            for (int hd = 0; hd < N_HEADS; ++hd) {
                float v = as_[s0 * N_HEADS + hd] + adn[hd];
                v = (v >= 0.f) ? v : NEG_SLOPE * v;
                const int iv = __float_as_int(v);
                const unsigned key = (iv < 0) ? ~(unsigned)iv
                                              : ((unsigned)iv | 0x80000000u);
                atomicMax(&msegu[hd], key);
            }
        }
    }
    __syncthreads();

    float mx[N_HEADS];
#pragma unroll
    for (int hd = 0; hd < N_HEADS; ++hd) {
        const unsigned key = msegu[hd];
        const int im = (key & 0x80000000u) ? (int)(key & 0x7fffffffu) : (int)~key;
        mx[hd] = __int_as_float(im);
    }

    // pass B: exp, denominator, unnormalized attention row (dups sum -> correct)
    for (int e = t; e < E_TOT; e += 256) {
        int s0, d;
        if (e < E_BASE) { s0 = edge_index[e]; d = edge_index[E_BASE + e]; }
        else            { s0 = e - E_BASE;    d = s0; }
        if (d == n) {
#pragma unroll
            for (int hd = 0; hd < N_HEADS; ++hd) {
                float v = as_[s0 * N_HEADS + hd] + adn[hd];
                v = (v >= 0.f) ? v : NEG_SLOPE * v;
                const float ex = expf(v - mx[hd]);
                atomicAdd(&dseg[hd], ex);
                atomicAdd(&M[s0][hd], ex);
            }
        }
    }
    __syncthreads();

    if (t < N_NODES * N_HEADS) ((float*)M)[t] /= dseg[t & 3];
    __syncthreads();

    // aggregation: thread t owns output column t
    const int head = t >> 6;
    float acc = 0.f;
#pragma unroll
    for (int s0 = 0; s0 < N_NODES; ++s0)
        acc += M[s0][head] * h[s0 * CDIM + t];        // h coalesced, L2-hot
    const float v = acc + gat_bias[t];
    sv[t] = v / (1.0f + expf(-v));                    // SiLU
    __syncthreads();

    // classifier: 8 partial groups x 32 cols, then LDS tree reduce
    const int j = t & 31, g = t >> 5;
    float a = 0.f;
#pragma unroll
    for (int c0 = 0; c0 < 32; ++c0) {
        const int c = g * 32 + c0;
        a += sv[c] * clsw[c * 32 + j];
    }
    red[g][j] = a;
    __syncthreads();
    if (t < 32) {
        float s2 = cls_b[t];
#pragma unroll
        for (int g2 = 0; g2 < 8; ++g2) s2 += red[g2][t];
        out[n * 32 + t] = s2;
    }
}

// ---------------------------------------------------------------------------
extern "C" void kernel_launch(void* const* d_in, const int* in_sizes, int n_in,
                              void* d_out, int out_size, void* d_ws, size_t ws_size,
                              hipStream_t stream) {
    const float* roi   = (const float*)d_in[0];
    const int*   eidx  = (const int*)d_in[1];
    const float* W     = (const float*)d_in[2];
    const float* a_src = (const float*)d_in[3];
    const float* a_dst = (const float*)d_in[4];
    const float* gbias = (const float*)d_in[5];
    const float* clsW  = (const float*)d_in[6];
    const float* clsb  = (const float*)d_in[7];
    float* out = (float*)d_out;

    float* x   = (float*)d_ws;                 // 32*256 floats
    float* h   = x + N_NODES * CDIM;           // 32*256 floats
    float* as_ = h + N_NODES * CDIM;           // 128 floats
    float* ad_ = as_ + N_NODES * N_HEADS;      // 128 floats

    pool_kernel<<<(N_NODES * CDIM) / 4, 256, 0, stream>>>(roi, x);
    h_kernel<<<N_NODES, 256, 0, stream>>>(x, W, a_src, a_dst, h, as_, ad_);
    gat_kernel<<<N_NODES, 256, 0, stream>>>(eidx, h, as_, ad_, gbias, clsW, clsb, out);
}